// Round 9
// baseline (546.947 us; speedup 1.0000x reference)
//
#include <hip/hip_runtime.h>

#define FD 128
#define SB 512

typedef __attribute__((ext_vector_type(8))) short bf16x8;
typedef __attribute__((ext_vector_type(4))) float f32x4;

static inline size_t roundup256(size_t x) { return (x + 255) & ~(size_t)255; }

__device__ __forceinline__ unsigned short f2bf(float f) {
    unsigned u = __float_as_uint(f);
    u += 0x7FFFu + ((u >> 16) & 1u);
    return (unsigned short)(u >> 16);
}
__device__ __forceinline__ float bflo(unsigned v) { return __uint_as_float(v << 16); }
__device__ __forceinline__ float bfhi(unsigned v) { return __uint_as_float(v & 0xFFFF0000u); }

// ---------------------------------------------------------------------------
// Device building blocks (composed into mega-kernels)
// ---------------------------------------------------------------------------

// W (f32 [128][128]) -> bf16 fragment order; vbid in [0,256)
__device__ __forceinline__ void dev_wprep(int vbid, int tid,
    const float* w0, const float* w1, const float* w2, const float* w3,
    unsigned short* out)
{
    const int widx = vbid >> 6;
    const float* src = (widx == 0) ? w0 : (widx == 1) ? w1 : (widx == 2) ? w2 : w3;
    const int flat = (vbid & 63) * 256 + tid;      // k*128 + n
    const int k = flat >> 7, n = flat & 127;
    const int dest = ((((n >> 4) * 4 + (k >> 5)) * 4 + ((k >> 3) & 3)) * 16 + (n & 15)) * 8 + (k & 7);
    out[widx * 16384 + dest] = f2bf(src[flat]);
}

// histogram + rank, 2 edges/thread; bins are LOCAL (0..N-1)
__device__ __forceinline__ void dev_hist(int vbid, int tid,
    const int* __restrict__ edst, int* __restrict__ deg, int* __restrict__ rank, int E)
{
    const int k0 = vbid * 512 + tid;
    const int k1 = k0 + 256;
    if (k0 < E) rank[k0] = atomicAdd(&deg[edst[k0]], 1);
    if (k1 < E) rank[k1] = atomicAdd(&deg[edst[k1]], 1);
}

// atomic-free scatter, 2 edges/thread; esorted gets GLOBAL src = srcOff + src
__device__ __forceinline__ void dev_scatter(int vbid, int tid,
    const int* __restrict__ esrc, const int* __restrict__ edst,
    const int* __restrict__ rowptr, const int* __restrict__ rank,
    int* __restrict__ esorted, int E, int srcOff)
{
    const int k0 = vbid * 512 + tid;
    const int k1 = k0 + 256;
    if (k0 < E) esorted[rowptr[edst[k0]] + rank[k0]] = srcOff + esrc[k0];
    if (k1 < E) esorted[rowptr[edst[k1]] + rank[k1]] = srcOff + esrc[k1];
}

// MFMA GEMM strip for one branch; all row pointers pre-offset to branch base.
// Fragment layouts (verified R7/R8): A: lane l holds A[l&15][8*(l>>4)+j];
// B frag order from dev_wprep; D: row=(l>>4)*4+reg, col=l&15.
template<bool A_F32>
__device__ __forceinline__ void dev_gemm(int bx, int tid,
    const float* __restrict__ Xf, const unsigned short* __restrict__ Xb,
    const unsigned short* __restrict__ Wb,
    const float* __restrict__ a_s, const float* __restrict__ a_d,
    unsigned short* __restrict__ H16, float* __restrict__ als, float* __restrict__ ald,
    int nrows)
{
    const int w = tid >> 6, l = tid & 63, lg = l >> 4, cl = l & 15;
    const int lr0 = bx * 64 + w * 16;
    const int lr  = lr0 + cl;

    bf16x8 a[4];
    if (lr < nrows) {
        if (A_F32) {
            const float* xp = Xf + (size_t)lr * FD + lg * 8;
            #pragma unroll
            for (int ks = 0; ks < 4; ++ks) {
                const float4 v0 = *(const float4*)(xp + ks * 32);
                const float4 v1 = *(const float4*)(xp + ks * 32 + 4);
                bf16x8 t;
                t[0] = (short)f2bf(v0.x); t[1] = (short)f2bf(v0.y);
                t[2] = (short)f2bf(v0.z); t[3] = (short)f2bf(v0.w);
                t[4] = (short)f2bf(v1.x); t[5] = (short)f2bf(v1.y);
                t[6] = (short)f2bf(v1.z); t[7] = (short)f2bf(v1.w);
                a[ks] = t;
            }
        } else {
            const unsigned short* xp = Xb + (size_t)lr * FD + lg * 8;
            #pragma unroll
            for (int ks = 0; ks < 4; ++ks) a[ks] = *(const bf16x8*)(xp + ks * 32);
        }
    } else {
        #pragma unroll
        for (int ks = 0; ks < 4; ++ks)
            #pragma unroll
            for (int j = 0; j < 8; ++j) a[ks][j] = 0;
    }

    f32x4 acc[8];
    #pragma unroll
    for (int t = 0; t < 8; ++t)
        #pragma unroll
        for (int j = 0; j < 4; ++j) acc[t][j] = 0.f;

    #pragma unroll
    for (int t = 0; t < 8; ++t) {
        #pragma unroll
        for (int ks = 0; ks < 4; ++ks) {
            const bf16x8 b = *(const bf16x8*)&Wb[(((t * 4 + ks) * 4 + lg) * 16 + cl) * 8];
            acc[t] = __builtin_amdgcn_mfma_f32_16x16x32_bf16(a[ks], b, acc[t], 0, 0, 0);
        }
    }

    float asv[8], adv[8];
    #pragma unroll
    for (int t = 0; t < 8; ++t) { asv[t] = a_s[t * 16 + cl]; adv[t] = a_d[t * 16 + cl]; }

    #pragma unroll
    for (int jj = 0; jj < 4; ++jj) {
        const int lrow = lr0 + 4 * lg + jj;
        float ps = 0.f, pd = 0.f;
        #pragma unroll
        for (int t = 0; t < 8; ++t) {
            ps = fmaf(acc[t][jj], asv[t], ps);
            pd = fmaf(acc[t][jj], adv[t], pd);
        }
        #pragma unroll
        for (int off = 8; off; off >>= 1) {
            ps += __shfl_down(ps, off, 16);
            pd += __shfl_down(pd, off, 16);
        }
        if (lrow < nrows) {
            #pragma unroll
            for (int t = 0; t < 8; ++t)
                H16[(size_t)lrow * FD + t * 16 + cl] = f2bf(acc[t][jj]);
            if (cl == 0) { als[lrow] = ps; ald[lrow] = pd; }
        }
    }
}

// GAT aggregation for one branch: rowptr/esorted local to branch (esorted has
// global src rows); als/ald/H16/out16 are FULL arrays, rows at d = dbase + dl.
__device__ __forceinline__ void dev_agg(int vbid, int tid,
    const int* __restrict__ rowptr, const int* __restrict__ esorted,
    const float* __restrict__ als, const float* __restrict__ ald,
    const unsigned short* __restrict__ H16, const float* __restrict__ bias,
    unsigned short* __restrict__ out16, int dbase, int n)
{
    const int dl   = (vbid * 256 + tid) >> 5;
    const int lane = tid & 31;
    if (dl >= n) return;
    const int d = dbase + dl;
    const int start = rowptr[dl], end = rowptr[dl + 1];
    const int deg = end - start;
    const float ald_d = ald[d];
    const int c = lane * 4;

    const uint2 hs = *(const uint2*)&H16[(size_t)d * FD + c];

    float e_self = als[d] + ald_d;
    e_self = fmaxf(e_self, 0.2f * e_self);

    float e_reg = -INFINITY;
    int src_reg = 0;
    if (lane < deg) {
        src_reg = esorted[start + lane];
        float t = als[src_reg] + ald_d;
        e_reg = fmaxf(t, 0.2f * t);
    }
    float m = e_reg;
    for (int j = start + 32 + lane; j < end; j += 32) {
        float t = als[esorted[j]] + ald_d;
        m = fmaxf(m, fmaxf(t, 0.2f * t));
    }
    #pragma unroll
    for (int off = 16; off; off >>= 1) m = fmaxf(m, __shfl_xor(m, off, 32));
    m = fmaxf(m, e_self);

    const float w_self = __expf(e_self - m);
    const float w_reg  = __expf(e_reg - m);

    float dsum = w_reg;
    #pragma unroll
    for (int off = 16; off; off >>= 1) dsum += __shfl_xor(dsum, off, 32);
    float denom = dsum + w_self;

    float a0 = w_self * bflo(hs.x);
    float a1 = w_self * bfhi(hs.x);
    float a2 = w_self * bflo(hs.y);
    float a3 = w_self * bfhi(hs.y);

    const int dmin = deg < 32 ? deg : 32;
    int j = 0;
    for (; j + 7 < dmin; j += 8) {
        uint2 hv[8];
        float w[8];
        #pragma unroll
        for (int q = 0; q < 8; ++q) {
            const int s = __shfl(src_reg, j + q, 32);
            w[q] = __shfl(w_reg, j + q, 32);
            hv[q] = *(const uint2*)&H16[(size_t)s * FD + c];
        }
        #pragma unroll
        for (int q = 0; q < 8; ++q) {
            a0 = fmaf(w[q], bflo(hv[q].x), a0);
            a1 = fmaf(w[q], bfhi(hv[q].x), a1);
            a2 = fmaf(w[q], bflo(hv[q].y), a2);
            a3 = fmaf(w[q], bfhi(hv[q].y), a3);
        }
    }
    for (; j < dmin; ++j) {
        const int   s = __shfl(src_reg, j, 32);
        const float w = __shfl(w_reg, j, 32);
        const uint2 hv = *(const uint2*)&H16[(size_t)s * FD + c];
        a0 = fmaf(w, bflo(hv.x), a0);
        a1 = fmaf(w, bfhi(hv.x), a1);
        a2 = fmaf(w, bflo(hv.y), a2);
        a3 = fmaf(w, bfhi(hv.y), a3);
    }
    for (int jj = 32; jj < deg; ++jj) {
        const int s = esorted[start + jj];
        float t = als[s] + ald_d;
        t = fmaxf(t, 0.2f * t);
        const float w = __expf(t - m);
        denom += w;
        const uint2 hv = *(const uint2*)&H16[(size_t)s * FD + c];
        a0 = fmaf(w, bflo(hv.x), a0);
        a1 = fmaf(w, bfhi(hv.x), a1);
        a2 = fmaf(w, bflo(hv.y), a2);
        a3 = fmaf(w, bfhi(hv.y), a3);
    }
    const float inv = 1.f / denom;
    const float4 bb = *(const float4*)&bias[c];
    const float o0 = fmaxf(fmaf(a0, inv, bb.x), 0.f);
    const float o1 = fmaxf(fmaf(a1, inv, bb.y), 0.f);
    const float o2 = fmaxf(fmaf(a2, inv, bb.z), 0.f);
    const float o3 = fmaxf(fmaf(a3, inv, bb.w), 0.f);
    uint2 ov;
    ov.x = (unsigned)f2bf(o0) | ((unsigned)f2bf(o1) << 16);
    ov.y = (unsigned)f2bf(o2) | ((unsigned)f2bf(o3) << 16);
    *(uint2*)&out16[(size_t)d * FD + c] = ov;
}

// ---------------------------------------------------------------------------
// Kernels
// ---------------------------------------------------------------------------

__global__ __launch_bounds__(256) void wprep_kernel(
    const float* __restrict__ w0, const float* __restrict__ w1,
    const float* __restrict__ w2, const float* __restrict__ w3,
    unsigned short* __restrict__ out)
{
    dev_wprep(blockIdx.x, threadIdx.x, w0, w1, w2, w3, out);
}

// M1: hist_td || GEMM-L1 both branches
__global__ __launch_bounds__(256) void mega_hist_gemm1_kernel(
    const int* __restrict__ td_ei, int* __restrict__ deg, int* __restrict__ rank,
    int E, int HB,
    const float* __restrict__ x, const unsigned short* __restrict__ wfrag,
    const float* __restrict__ td_as1, const float* __restrict__ td_ad1,
    const float* __restrict__ bu_as1, const float* __restrict__ bu_ad1,
    unsigned short* __restrict__ h16, float* __restrict__ als, float* __restrict__ ald,
    int N, int gx)
{
    int bid = blockIdx.x;
    const int tid = threadIdx.x;
    if (bid < HB) { dev_hist(bid, tid, td_ei + E, deg, rank, E); return; }
    bid -= HB;
    if (bid < gx)
        dev_gemm<true>(bid, tid, x, nullptr, wfrag, td_as1, td_ad1, h16, als, ald, N);
    else
        dev_gemm<true>(bid - gx, tid, x, nullptr, wfrag + 16384, bu_as1, bu_ad1,
                       h16 + (size_t)N * FD, als + N, ald + N, N);
}

// standalone scatter (td)
__global__ __launch_bounds__(256) void scatter_kernel(
    const int* __restrict__ ei, const int* __restrict__ rowptr,
    const int* __restrict__ rank, int* __restrict__ esorted, int E, int srcOff)
{
    dev_scatter(blockIdx.x, threadIdx.x, ei, ei + E, rowptr, rank, esorted, E, srcOff);
}

// M2: hist_bu || aggregate-L1 td
__global__ __launch_bounds__(256) void mega_agg_hist_kernel(
    const int* __restrict__ bu_ei, int* __restrict__ deg, int* __restrict__ rank,
    int E, int HB,
    const int* __restrict__ rowptr_td, const int* __restrict__ esorted_td,
    const float* __restrict__ als, const float* __restrict__ ald,
    const unsigned short* __restrict__ h16, const float* __restrict__ td_b1,
    unsigned short* __restrict__ o16, int N)
{
    const int bid = blockIdx.x;
    const int tid = threadIdx.x;
    if (bid < HB) { dev_hist(bid, tid, bu_ei + E, deg, rank, E); return; }
    dev_agg(bid - HB, tid, rowptr_td, esorted_td, als, ald, h16, td_b1, o16, 0, N);
}

// M3: GEMM-L2 td || scatter_bu
__global__ __launch_bounds__(256) void mega_gemm_scatter_kernel(
    const unsigned short* __restrict__ o16, const unsigned short* __restrict__ wfrag_td2,
    const float* __restrict__ td_as2, const float* __restrict__ td_ad2,
    unsigned short* __restrict__ h16, float* __restrict__ als, float* __restrict__ ald,
    int N, int gx,
    const int* __restrict__ bu_ei, const int* __restrict__ rowptr_bu,
    const int* __restrict__ rank, int* __restrict__ esorted_bu, int E)
{
    const int bid = blockIdx.x;
    const int tid = threadIdx.x;
    if (bid < gx) {
        dev_gemm<false>(bid, tid, nullptr, o16, wfrag_td2, td_as2, td_ad2, h16, als, ald, N);
        return;
    }
    dev_scatter(bid - gx, tid, bu_ei, bu_ei + E, rowptr_bu, rank, esorted_bu, E, N);
}

// M4: aggregate-L2 td || aggregate-L1 bu
__global__ __launch_bounds__(256) void mega_agg2_kernel(
    const int* __restrict__ rowptr_td, const int* __restrict__ esorted_td,
    const float* __restrict__ td_b2,
    const int* __restrict__ rowptr_bu, const int* __restrict__ esorted_bu,
    const float* __restrict__ bu_b1,
    const float* __restrict__ als, const float* __restrict__ ald,
    const unsigned short* __restrict__ h16, unsigned short* __restrict__ o16,
    int N, int AB)
{
    const int bid = blockIdx.x;
    const int tid = threadIdx.x;
    if (bid < AB) dev_agg(bid, tid, rowptr_td, esorted_td, als, ald, h16, td_b2, o16, 0, N);
    else          dev_agg(bid - AB, tid, rowptr_bu, esorted_bu, als, ald, h16, bu_b1, o16, N, N);
}

// plain GEMM (bu layer 2)
__global__ __launch_bounds__(256) void gemm_bf16_kernel(
    const unsigned short* __restrict__ Xb, const unsigned short* __restrict__ Wb,
    const float* __restrict__ a_s, const float* __restrict__ a_d,
    unsigned short* __restrict__ H16, float* __restrict__ als, float* __restrict__ ald,
    int nrows)
{
    dev_gemm<false>(blockIdx.x, threadIdx.x, nullptr, Xb, Wb, a_s, a_d, H16, als, ald, nrows);
}

// plain aggregate (bu layer 2)
__global__ __launch_bounds__(256) void agg_kernel(
    const int* __restrict__ rowptr, const int* __restrict__ esorted,
    const float* __restrict__ als, const float* __restrict__ ald,
    const unsigned short* __restrict__ h16, const float* __restrict__ bias,
    unsigned short* __restrict__ o16, int dbase, int n)
{
    dev_agg(blockIdx.x, threadIdx.x, rowptr, esorted, als, ald, h16, bias, o16, dbase, n);
}

// ---------------------------------------------------------------------------
// scans (per branch, N bins)
// ---------------------------------------------------------------------------
__global__ __launch_bounds__(SB) void scan_block_kernel(
    const int* __restrict__ in, int* __restrict__ out, int* __restrict__ bsum, int n)
{
    __shared__ int sh[SB];
    const int tid = threadIdx.x;
    const int i = blockIdx.x * SB + tid;
    int v = (i < n) ? in[i] : 0;
    sh[tid] = v;
    __syncthreads();
    for (int off = 1; off < SB; off <<= 1) {
        int t = (tid >= off) ? sh[tid - off] : 0;
        __syncthreads();
        sh[tid] += t;
        __syncthreads();
    }
    if (i < n) out[i] = sh[tid] - v;
    if (tid == SB - 1) bsum[blockIdx.x] = sh[tid];
}

__global__ __launch_bounds__(SB) void scan_top_kernel(int* __restrict__ bsum, int nb)
{
    __shared__ int sh[SB];
    const int tid = threadIdx.x;
    int v = (tid < nb) ? bsum[tid] : 0;
    sh[tid] = v;
    __syncthreads();
    for (int off = 1; off < SB; off <<= 1) {
        int t = (tid >= off) ? sh[tid - off] : 0;
        __syncthreads();
        sh[tid] += t;
        __syncthreads();
    }
    if (tid < nb) bsum[tid] = sh[tid] - v;
}

__global__ __launch_bounds__(SB) void scan_add_kernel(
    int* __restrict__ rowptr, const int* __restrict__ bsum, int n, int total)
{
    int i = blockIdx.x * SB + threadIdx.x;
    if (i < n) rowptr[i] += bsum[blockIdx.x];
    if (i == 0) rowptr[n] = total;
}

// ---------------------------------------------------------------------------
// pool + fc
// ---------------------------------------------------------------------------
__global__ __launch_bounds__(256) void pool_mean_kernel(
    const unsigned short* __restrict__ Hb, const int* __restrict__ batch,
    float* __restrict__ pooled_td, float* __restrict__ pooled_bu, int n)
{
    __shared__ float sh[3][FD];
    const int g = blockIdx.x;
    const int br = blockIdx.y;
    int lo = 0, hi = n;
    while (lo < hi) { int mid = (lo + hi) >> 1; if (batch[mid] < g) lo = mid + 1; else hi = mid; }
    int start = lo;
    hi = n;
    while (lo < hi) { int mid = (lo + hi) >> 1; if (batch[mid] < g + 1) lo = mid + 1; else hi = mid; }
    int end = lo;
    const int cp = threadIdx.x & 63;
    const int q  = threadIdx.x >> 6;
    const size_t rbase = (size_t)br * n;
    float ax = 0.f, ay = 0.f;
    for (int i = start + q; i < end; i += 4) {
        unsigned v = ((const unsigned*)Hb)[(rbase + i) * 64 + cp];
        ax += bflo(v);
        ay += bfhi(v);
    }
    if (q) { sh[q - 1][cp * 2] = ax; sh[q - 1][cp * 2 + 1] = ay; }
    __syncthreads();
    if (!q) {
        float tx = ax + sh[0][cp * 2] + sh[1][cp * 2] + sh[2][cp * 2];
        float ty = ay + sh[0][cp * 2 + 1] + sh[1][cp * 2 + 1] + sh[2][cp * 2 + 1];
        float inv = 1.f / fmaxf((float)(end - start), 1.f);
        float* out = br ? pooled_bu : pooled_td;
        out[(size_t)g * FD + cp * 2]     = tx * inv;
        out[(size_t)g * FD + cp * 2 + 1] = ty * inv;
    }
}

__global__ __launch_bounds__(256) void fc_logsoftmax_kernel(
    const float* __restrict__ bu, const float* __restrict__ td,
    const float* __restrict__ Wf, const float* __restrict__ bf,
    float* __restrict__ out, int g)
{
    const int wid  = (int)((blockIdx.x * 256u + threadIdx.x) >> 6);
    const int lane = threadIdx.x & 63;
    if (wid >= g) return;
    const float f0 = bu[(size_t)wid * FD + lane];
    const float f1 = bu[(size_t)wid * FD + 64 + lane];
    const float f2 = td[(size_t)wid * FD + lane];
    const float f3 = td[(size_t)wid * FD + 64 + lane];
    const float4 w0 = *(const float4*)&Wf[lane * 4];
    const float4 w1 = *(const float4*)&Wf[(64 + lane) * 4];
    const float4 w2 = *(const float4*)&Wf[(128 + lane) * 4];
    const float4 w3 = *(const float4*)&Wf[(192 + lane) * 4];
    float l0 = f0 * w0.x + f1 * w1.x + f2 * w2.x + f3 * w3.x;
    float l1 = f0 * w0.y + f1 * w1.y + f2 * w2.y + f3 * w3.y;
    float l2 = f0 * w0.z + f1 * w1.z + f2 * w2.z + f3 * w3.z;
    float l3 = f0 * w0.w + f1 * w1.w + f2 * w2.w + f3 * w3.w;
    #pragma unroll
    for (int off = 32; off; off >>= 1) {
        l0 += __shfl_xor(l0, off, 64);
        l1 += __shfl_xor(l1, off, 64);
        l2 += __shfl_xor(l2, off, 64);
        l3 += __shfl_xor(l3, off, 64);
    }
    if (lane == 0) {
        l0 += bf[0]; l1 += bf[1]; l2 += bf[2]; l3 += bf[3];
        float m = fmaxf(fmaxf(l0, l1), fmaxf(l2, l3));
        float ssum = expf(l0 - m) + expf(l1 - m) + expf(l2 - m) + expf(l3 - m);
        float ls = logf(ssum);
        out[(size_t)wid * 4 + 0] = l0 - m - ls;
        out[(size_t)wid * 4 + 1] = l1 - m - ls;
        out[(size_t)wid * 4 + 2] = l2 - m - ls;
        out[(size_t)wid * 4 + 3] = l3 - m - ls;
    }
}

extern "C" void kernel_launch(void* const* d_in, const int* in_sizes, int n_in,
                              void* d_out, int out_size, void* d_ws, size_t ws_size,
                              hipStream_t stream)
{
    const float* x      = (const float*)d_in[0];
    const int*   td_ei  = (const int*)d_in[1];
    const int*   bu_ei  = (const int*)d_in[2];
    const int*   batch  = (const int*)d_in[3];
    const float* td_as1 = (const float*)d_in[5];
    const float* td_ad1 = (const float*)d_in[6];
    const float* td_b1  = (const float*)d_in[7];
    const float* td_as2 = (const float*)d_in[9];
    const float* td_ad2 = (const float*)d_in[10];
    const float* td_b2  = (const float*)d_in[11];
    const float* bu_as1 = (const float*)d_in[13];
    const float* bu_ad1 = (const float*)d_in[14];
    const float* bu_b1  = (const float*)d_in[15];
    const float* bu_as2 = (const float*)d_in[17];
    const float* bu_ad2 = (const float*)d_in[18];
    const float* bu_b2  = (const float*)d_in[19];
    const float* fc_W   = (const float*)d_in[20];
    const float* fc_b   = (const float*)d_in[21];
    const float* td_W1  = (const float*)d_in[4];
    const float* td_W2  = (const float*)d_in[8];
    const float* bu_W1  = (const float*)d_in[12];
    const float* bu_W2  = (const float*)d_in[16];

    const int N  = in_sizes[0] / FD;
    const int E  = in_sizes[1] / 2;
    const int G  = out_size / 4;
    const int nb = (N + SB - 1) / SB;
    const int gx = (N + 63) / 64;        // gemm strips per branch
    const int HB = (E + 511) / 512;      // hist/scatter blocks (2 edges/thread)
    const int AB = (N + 7) / 8;          // aggregate blocks per branch

    char* p = (char*)d_ws;
    unsigned short* h16 = (unsigned short*)p; p += roundup256((size_t)2 * N * FD * 2);
    unsigned short* o16 = (unsigned short*)p; p += roundup256((size_t)2 * N * FD * 2);
    int* esorted_td = (int*)p; p += roundup256((size_t)E * 4);
    int* esorted_bu = (int*)p; p += roundup256((size_t)E * 4);
    int* rank   = (int*)p;    p += roundup256((size_t)E * 4);   // reused td then bu
    float* als  = (float*)p;  p += roundup256((size_t)2 * N * 4);
    float* ald  = (float*)p;  p += roundup256((size_t)2 * N * 4);
    int* rowptr_td = (int*)p; p += roundup256((size_t)(N + 1) * 4);
    int* rowptr_bu = (int*)p; p += roundup256((size_t)(N + 1) * 4);
    int* deg    = (int*)p;    p += roundup256((size_t)N * 4);   // reused td then bu
    int* bsum   = (int*)p;    p += roundup256((size_t)SB * 4);
    unsigned short* wfrag = (unsigned short*)p; p += roundup256((size_t)4 * 16384 * 2);
    float* pooled_td = (float*)p; p += roundup256((size_t)G * FD * 4);
    float* pooled_bu = (float*)p; p += roundup256((size_t)G * FD * 4);

    const dim3 blk256(256);

    // W fragment prep (must precede M1 — M1's GEMM reads wfrag)
    wprep_kernel<<<dim3(256), blk256, 0, stream>>>(td_W1, bu_W1, td_W2, bu_W2, wfrag);
    hipMemsetAsync(deg, 0, (size_t)N * 4, stream);

    // M1: hist_td || GEMM-L1 (both branches)
    mega_hist_gemm1_kernel<<<dim3(HB + 2 * gx), blk256, 0, stream>>>(
        td_ei, deg, rank, E, HB,
        x, wfrag, td_as1, td_ad1, bu_as1, bu_ad1, h16, als, ald, N, gx);

    // scan td
    scan_block_kernel<<<dim3(nb), dim3(SB), 0, stream>>>(deg, rowptr_td, bsum, N);
    scan_top_kernel<<<dim3(1), dim3(SB), 0, stream>>>(bsum, nb);
    scan_add_kernel<<<dim3(nb), dim3(SB), 0, stream>>>(rowptr_td, bsum, N, E);

    // scatter td
    scatter_kernel<<<dim3(HB), blk256, 0, stream>>>(td_ei, rowptr_td, rank, esorted_td, E, 0);
    hipMemsetAsync(deg, 0, (size_t)N * 4, stream);

    // M2: hist_bu || aggregate-L1 td  (o16[0,N) written)
    mega_agg_hist_kernel<<<dim3(HB + AB), blk256, 0, stream>>>(
        bu_ei, deg, rank, E, HB,
        rowptr_td, esorted_td, als, ald, h16, td_b1, o16, N);

    // scan bu
    scan_block_kernel<<<dim3(nb), dim3(SB), 0, stream>>>(deg, rowptr_bu, bsum, N);
    scan_top_kernel<<<dim3(1), dim3(SB), 0, stream>>>(bsum, nb);
    scan_add_kernel<<<dim3(nb), dim3(SB), 0, stream>>>(rowptr_bu, bsum, N, E);

    // M3: GEMM-L2 td (o16[0,N) -> h16[0,N), als/ald[0,N)) || scatter_bu
    mega_gemm_scatter_kernel<<<dim3(gx + HB), blk256, 0, stream>>>(
        o16, wfrag + 2 * 16384, td_as2, td_ad2, h16, als, ald, N, gx,
        bu_ei, rowptr_bu, rank, esorted_bu, E);

    // M4: aggregate-L2 td (-> o16[0,N), final) || aggregate-L1 bu (-> o16[N,2N))
    mega_agg2_kernel<<<dim3(2 * AB), blk256, 0, stream>>>(
        rowptr_td, esorted_td, td_b2,
        rowptr_bu, esorted_bu, bu_b1,
        als, ald, h16, o16, N, AB);

    // GEMM-L2 bu: o16[N,2N) -> h16[N,2N), als/ald[N,2N)
    gemm_bf16_kernel<<<dim3(gx), blk256, 0, stream>>>(
        o16 + (size_t)N * FD, wfrag + 3 * 16384, bu_as2, bu_ad2,
        h16 + (size_t)N * FD, als + N, ald + N, N);

    // aggregate-L2 bu -> o16[N,2N) final
    agg_kernel<<<dim3(AB), blk256, 0, stream>>>(
        rowptr_bu, esorted_bu, als, ald, h16, bu_b2, o16, N, N);

    // pool (both branches) + fc
    pool_mean_kernel<<<dim3(G, 2), blk256, 0, stream>>>(o16, batch, pooled_td, pooled_bu, N);
    fc_logsoftmax_kernel<<<dim3((G + 3) / 4), blk256, 0, stream>>>(
        pooled_bu, pooled_td, fc_W, fc_b, (float*)d_out, G);
}

// Round 10
// 418.603 us; speedup vs baseline: 1.3066x; 1.3066x over previous
//
#include <hip/hip_runtime.h>

#define FD 128
#define SB 512
#define CHK 8192   // edges per bucket-count/scatter block

typedef __attribute__((ext_vector_type(8))) short bf16x8;
typedef __attribute__((ext_vector_type(4))) float f32x4;

static inline size_t roundup256(size_t x) { return (x + 255) & ~(size_t)255; }

__device__ __forceinline__ unsigned short f2bf(float f) {
    unsigned u = __float_as_uint(f);
    u += 0x7FFFu + ((u >> 16) & 1u);
    return (unsigned short)(u >> 16);
}
__device__ __forceinline__ float bflo(unsigned v) { return __uint_as_float(v << 16); }
__device__ __forceinline__ float bfhi(unsigned v) { return __uint_as_float(v & 0xFFFF0000u); }

// ---------------------------------------------------------------------------
// W (f32 [128][128]) -> bf16 MFMA-fragment order, 4 matrices.
// ---------------------------------------------------------------------------
__global__ __launch_bounds__(256) void wprep_kernel(
    const float* __restrict__ w0, const float* __restrict__ w1,
    const float* __restrict__ w2, const float* __restrict__ w3,
    unsigned short* __restrict__ out)
{
    const int widx = blockIdx.x >> 6;
    const float* src = (widx == 0) ? w0 : (widx == 1) ? w1 : (widx == 2) ? w2 : w3;
    const int flat = (blockIdx.x & 63) * 256 + threadIdx.x;   // k*128 + n
    const int k = flat >> 7, n = flat & 127;
    const int dest = ((((n >> 4) * 4 + (k >> 5)) * 4 + ((k >> 3) & 3)) * 16 + (n & 15)) * 8 + (k & 7);
    out[widx * 16384 + dest] = f2bf(src[flat]);
}

// ---------------------------------------------------------------------------
// Atomic-free CSR build (both branches). Coarse bucket = dst>>8.
// table layout: [(br*NB + bucket) * NBLK + block] ; after scan = global offsets.
// ---------------------------------------------------------------------------
__global__ __launch_bounds__(256) void bucket_count_kernel(
    const int* __restrict__ td_ei, const int* __restrict__ bu_ei,
    int* __restrict__ table, int E, int NB, int NBLK)
{
    __shared__ int cnt[512];
    const int blk = blockIdx.x;
    const int br = blk / NBLK, c = blk % NBLK;
    const int* edst = (br ? bu_ei : td_ei) + E;
    for (int i = threadIdx.x; i < NB; i += 256) cnt[i] = 0;
    __syncthreads();
    const int k0 = c * CHK;
    #pragma unroll 4
    for (int j = 0; j < CHK / 256; ++j) {
        const int k = k0 + j * 256 + threadIdx.x;
        if (k < E) atomicAdd(&cnt[((unsigned)edst[k]) >> 8], 1);
    }
    __syncthreads();
    for (int i = threadIdx.x; i < NB; i += 256)
        table[(br * NB + i) * NBLK + c] = cnt[i];
}

__global__ __launch_bounds__(256) void bucket_scatter_kernel(
    const int* __restrict__ td_ei, const int* __restrict__ bu_ei,
    const int* __restrict__ scanned, int* __restrict__ bucketed,
    int E, int NB, int NBLK)
{
    __shared__ int cur[512];
    const int blk = blockIdx.x;
    const int br = blk / NBLK, c = blk % NBLK;
    const int* ei = br ? bu_ei : td_ei;
    for (int i = threadIdx.x; i < NB; i += 256)
        cur[i] = scanned[(br * NB + i) * NBLK + c];
    __syncthreads();
    const int k0 = c * CHK;
    #pragma unroll 4
    for (int j = 0; j < CHK / 256; ++j) {
        const int k = k0 + j * 256 + threadIdx.x;
        if (k < E) {
            const int d = ei[E + k], s = ei[k];
            const int pos = atomicAdd(&cur[((unsigned)d) >> 8], 1);
            bucketed[pos] = ((d & 255) << 24) | s;
        }
    }
}

// One block per bucket: local 256-bin sort -> rowptr + esorted (global rows).
__global__ __launch_bounds__(256) void bucket_finalize_kernel(
    const int* __restrict__ scanned, const int* __restrict__ bucketed,
    int* __restrict__ esorted, int* __restrict__ rowptr,
    int E, int N, int NB, int NBLK)
{
    __shared__ int bins[256], off[256], curs[256], tmp[256];
    const int gb = blockIdx.x;            // 0 .. 2*NB-1
    const int br = gb / NB, lb = gb % NB;
    const int tid = threadIdx.x;
    const int base = scanned[gb * NBLK];
    const int next = scanned[(gb + 1) * NBLK];   // last+1 entry = 2E (scan total)
    const int s = next - base;

    bins[tid] = 0;
    __syncthreads();
    for (int i = base + tid; i < base + s; i += 256)
        atomicAdd(&bins[((unsigned)bucketed[i]) >> 24], 1);
    __syncthreads();
    // exclusive scan of bins
    const int v = bins[tid];
    tmp[tid] = v;
    __syncthreads();
    for (int o = 1; o < 256; o <<= 1) {
        const int t = (tid >= o) ? tmp[tid - o] : 0;
        __syncthreads();
        tmp[tid] += t;
        __syncthreads();
    }
    off[tid] = tmp[tid] - v;
    curs[tid] = tmp[tid] - v;
    const int nd = N - lb * 256;
    if (tid < nd && tid < 256) rowptr[br * N + lb * 256 + tid] = base + off[tid];
    if (gb == 2 * NB - 1 && tid == 0) rowptr[2 * N] = 2 * E;
    __syncthreads();
    for (int i = base + tid; i < base + s; i += 256) {
        const int p = bucketed[i];
        const int r = atomicAdd(&curs[((unsigned)p) >> 24], 1);
        esorted[base + r] = br * N + (p & 0xFFFFFF);
    }
}

// ---------------------------------------------------------------------------
// generic scans (used for the bucket table; in-place safe)
// ---------------------------------------------------------------------------
__global__ __launch_bounds__(SB) void scan_block_kernel(
    const int* __restrict__ in, int* __restrict__ out, int* __restrict__ bsum, int n)
{
    __shared__ int sh[SB];
    const int tid = threadIdx.x;
    const int i = blockIdx.x * SB + tid;
    int v = (i < n) ? in[i] : 0;
    sh[tid] = v;
    __syncthreads();
    for (int off = 1; off < SB; off <<= 1) {
        int t = (tid >= off) ? sh[tid - off] : 0;
        __syncthreads();
        sh[tid] += t;
        __syncthreads();
    }
    if (i < n) out[i] = sh[tid] - v;
    if (tid == SB - 1) bsum[blockIdx.x] = sh[tid];
}

__global__ __launch_bounds__(SB) void scan_top_kernel(int* __restrict__ bsum, int nb)
{
    __shared__ int sh[SB];
    const int tid = threadIdx.x;
    int v = (tid < nb) ? bsum[tid] : 0;
    sh[tid] = v;
    __syncthreads();
    for (int off = 1; off < SB; off <<= 1) {
        int t = (tid >= off) ? sh[tid - off] : 0;
        __syncthreads();
        sh[tid] += t;
        __syncthreads();
    }
    if (tid < nb) bsum[tid] = sh[tid] - v;
}

__global__ __launch_bounds__(SB) void scan_add_kernel(
    int* __restrict__ arr, const int* __restrict__ bsum, int n, int total)
{
    int i = blockIdx.x * SB + threadIdx.x;
    if (i < n) arr[i] += bsum[blockIdx.x];
    if (i == 0) arr[n] = total;
}

// ---------------------------------------------------------------------------
// MFMA GEMM, both branches (blockIdx.y). h = A @ W_br; bf16 out + als/ald.
// ---------------------------------------------------------------------------
template<bool A_F32>
__global__ __launch_bounds__(256) void gemm_mfma_kernel(
    const float* __restrict__ Xf, const unsigned short* __restrict__ Xb,
    const unsigned short* __restrict__ Wfrag,
    const float* __restrict__ as0, const float* __restrict__ ad0,
    const float* __restrict__ as1, const float* __restrict__ ad1,
    unsigned short* __restrict__ H16, float* __restrict__ als, float* __restrict__ ald,
    int nrows, int xbstride)
{
    const int tid = threadIdx.x;
    const int br  = blockIdx.y;
    const int w = tid >> 6, l = tid & 63, lg = l >> 4, cl = l & 15;
    const int lr0 = blockIdx.x * 64 + w * 16;
    const int lr  = lr0 + cl;
    const unsigned short* Wb = Wfrag + br * 16384;
    const float* a_s = br ? as1 : as0;
    const float* a_d = br ? ad1 : ad0;

    bf16x8 a[4];
    if (lr < nrows) {
        if (A_F32) {
            const float* xp = Xf + (size_t)(br * xbstride + lr) * FD + lg * 8;
            #pragma unroll
            for (int ks = 0; ks < 4; ++ks) {
                const float4 v0 = *(const float4*)(xp + ks * 32);
                const float4 v1 = *(const float4*)(xp + ks * 32 + 4);
                bf16x8 t;
                t[0] = (short)f2bf(v0.x); t[1] = (short)f2bf(v0.y);
                t[2] = (short)f2bf(v0.z); t[3] = (short)f2bf(v0.w);
                t[4] = (short)f2bf(v1.x); t[5] = (short)f2bf(v1.y);
                t[6] = (short)f2bf(v1.z); t[7] = (short)f2bf(v1.w);
                a[ks] = t;
            }
        } else {
            const unsigned short* xp = Xb + (size_t)(br * xbstride + lr) * FD + lg * 8;
            #pragma unroll
            for (int ks = 0; ks < 4; ++ks) a[ks] = *(const bf16x8*)(xp + ks * 32);
        }
    } else {
        #pragma unroll
        for (int ks = 0; ks < 4; ++ks)
            #pragma unroll
            for (int j = 0; j < 8; ++j) a[ks][j] = 0;
    }

    f32x4 acc[8];
    #pragma unroll
    for (int t = 0; t < 8; ++t)
        #pragma unroll
        for (int j = 0; j < 4; ++j) acc[t][j] = 0.f;

    #pragma unroll
    for (int t = 0; t < 8; ++t) {
        #pragma unroll
        for (int ks = 0; ks < 4; ++ks) {
            const bf16x8 b = *(const bf16x8*)&Wb[(((t * 4 + ks) * 4 + lg) * 16 + cl) * 8];
            acc[t] = __builtin_amdgcn_mfma_f32_16x16x32_bf16(a[ks], b, acc[t], 0, 0, 0);
        }
    }

    float asv[8], adv[8];
    #pragma unroll
    for (int t = 0; t < 8; ++t) { asv[t] = a_s[t * 16 + cl]; adv[t] = a_d[t * 16 + cl]; }

    #pragma unroll
    for (int jj = 0; jj < 4; ++jj) {
        const int lrow = lr0 + 4 * lg + jj;
        float ps = 0.f, pd = 0.f;
        #pragma unroll
        for (int t = 0; t < 8; ++t) {
            ps = fmaf(acc[t][jj], asv[t], ps);
            pd = fmaf(acc[t][jj], adv[t], pd);
        }
        #pragma unroll
        for (int off = 8; off; off >>= 1) {
            ps += __shfl_down(ps, off, 16);
            pd += __shfl_down(pd, off, 16);
        }
        if (lrow < nrows) {
            const size_t grow = (size_t)br * nrows + lrow;
            #pragma unroll
            for (int t = 0; t < 8; ++t)
                H16[grow * FD + t * 16 + cl] = f2bf(acc[t][jj]);
            if (cl == 0) { als[grow] = ps; ald[grow] = pd; }
        }
    }
}

// ---------------------------------------------------------------------------
// Fused GAT aggregation, both branches (2N nodes), bf16 in/out.
// ---------------------------------------------------------------------------
__global__ __launch_bounds__(256) void gat_aggregate_kernel(
    const int* __restrict__ rowptr, const int* __restrict__ esorted,
    const float* __restrict__ als, const float* __restrict__ ald,
    const unsigned short* __restrict__ H16,
    const float* __restrict__ b0, const float* __restrict__ b1,
    unsigned short* __restrict__ out16, int n2, int N)
{
    const int d    = (int)((blockIdx.x * 256u + threadIdx.x) >> 5);
    const int lane = threadIdx.x & 31;
    if (d >= n2) return;
    const int start = rowptr[d], end = rowptr[d + 1];
    const int deg = end - start;
    const float ald_d = ald[d];
    const int c = lane * 4;
    const float* bias = (d < N) ? b0 : b1;

    const uint2 hs = *(const uint2*)&H16[(size_t)d * FD + c];

    float e_self = als[d] + ald_d;
    e_self = fmaxf(e_self, 0.2f * e_self);

    float e_reg = -INFINITY;
    int src_reg = 0;
    if (lane < deg) {
        src_reg = esorted[start + lane];
        float t = als[src_reg] + ald_d;
        e_reg = fmaxf(t, 0.2f * t);
    }
    float m = e_reg;
    for (int j = start + 32 + lane; j < end; j += 32) {
        float t = als[esorted[j]] + ald_d;
        m = fmaxf(m, fmaxf(t, 0.2f * t));
    }
    #pragma unroll
    for (int off = 16; off; off >>= 1) m = fmaxf(m, __shfl_xor(m, off, 32));
    m = fmaxf(m, e_self);

    const float w_self = __expf(e_self - m);
    const float w_reg  = __expf(e_reg - m);

    float dsum = w_reg;
    #pragma unroll
    for (int off = 16; off; off >>= 1) dsum += __shfl_xor(dsum, off, 32);
    float denom = dsum + w_self;

    float a0 = w_self * bflo(hs.x);
    float a1 = w_self * bfhi(hs.x);
    float a2 = w_self * bflo(hs.y);
    float a3 = w_self * bfhi(hs.y);

    const int dmin = deg < 32 ? deg : 32;
    int j = 0;
    for (; j + 7 < dmin; j += 8) {
        uint2 hv[8];
        float w[8];
        #pragma unroll
        for (int q = 0; q < 8; ++q) {
            const int s = __shfl(src_reg, j + q, 32);
            w[q] = __shfl(w_reg, j + q, 32);
            hv[q] = *(const uint2*)&H16[(size_t)s * FD + c];
        }
        #pragma unroll
        for (int q = 0; q < 8; ++q) {
            a0 = fmaf(w[q], bflo(hv[q].x), a0);
            a1 = fmaf(w[q], bfhi(hv[q].x), a1);
            a2 = fmaf(w[q], bflo(hv[q].y), a2);
            a3 = fmaf(w[q], bfhi(hv[q].y), a3);
        }
    }
    for (; j < dmin; ++j) {
        const int   s = __shfl(src_reg, j, 32);
        const float w = __shfl(w_reg, j, 32);
        const uint2 hv = *(const uint2*)&H16[(size_t)s * FD + c];
        a0 = fmaf(w, bflo(hv.x), a0);
        a1 = fmaf(w, bfhi(hv.x), a1);
        a2 = fmaf(w, bflo(hv.y), a2);
        a3 = fmaf(w, bfhi(hv.y), a3);
    }
    for (int jj = 32; jj < deg; ++jj) {
        const int s = esorted[start + jj];
        float t = als[s] + ald_d;
        t = fmaxf(t, 0.2f * t);
        const float w = __expf(t - m);
        denom += w;
        const uint2 hv = *(const uint2*)&H16[(size_t)s * FD + c];
        a0 = fmaf(w, bflo(hv.x), a0);
        a1 = fmaf(w, bfhi(hv.x), a1);
        a2 = fmaf(w, bflo(hv.y), a2);
        a3 = fmaf(w, bfhi(hv.y), a3);
    }
    const float inv = 1.f / denom;
    const float4 bb = *(const float4*)&bias[c];
    const float o0 = fmaxf(fmaf(a0, inv, bb.x), 0.f);
    const float o1 = fmaxf(fmaf(a1, inv, bb.y), 0.f);
    const float o2 = fmaxf(fmaf(a2, inv, bb.z), 0.f);
    const float o3 = fmaxf(fmaf(a3, inv, bb.w), 0.f);
    uint2 ov;
    ov.x = (unsigned)f2bf(o0) | ((unsigned)f2bf(o1) << 16);
    ov.y = (unsigned)f2bf(o2) | ((unsigned)f2bf(o3) << 16);
    *(uint2*)&out16[(size_t)d * FD + c] = ov;
}

// ---------------------------------------------------------------------------
// Mean-pool per graph, both branches (blockIdx.y). batch sorted, len N.
// ---------------------------------------------------------------------------
__global__ __launch_bounds__(256) void pool_mean_kernel(
    const unsigned short* __restrict__ Hb, const int* __restrict__ batch,
    float* __restrict__ pooled_td, float* __restrict__ pooled_bu, int n)
{
    __shared__ float sh[3][FD];
    const int g = blockIdx.x;
    const int br = blockIdx.y;
    int lo = 0, hi = n;
    while (lo < hi) { int mid = (lo + hi) >> 1; if (batch[mid] < g) lo = mid + 1; else hi = mid; }
    int start = lo;
    hi = n;
    while (lo < hi) { int mid = (lo + hi) >> 1; if (batch[mid] < g + 1) lo = mid + 1; else hi = mid; }
    int end = lo;
    const int cp = threadIdx.x & 63;
    const int q  = threadIdx.x >> 6;
    const size_t rbase = (size_t)br * n;
    float ax = 0.f, ay = 0.f;
    for (int i = start + q; i < end; i += 4) {
        unsigned v = ((const unsigned*)Hb)[(rbase + i) * 64 + cp];
        ax += bflo(v);
        ay += bfhi(v);
    }
    if (q) { sh[q - 1][cp * 2] = ax; sh[q - 1][cp * 2 + 1] = ay; }
    __syncthreads();
    if (!q) {
        float tx = ax + sh[0][cp * 2] + sh[1][cp * 2] + sh[2][cp * 2];
        float ty = ay + sh[0][cp * 2 + 1] + sh[1][cp * 2 + 1] + sh[2][cp * 2 + 1];
        float inv = 1.f / fmaxf((float)(end - start), 1.f);
        float* out = br ? pooled_bu : pooled_td;
        out[(size_t)g * FD + cp * 2]     = tx * inv;
        out[(size_t)g * FD + cp * 2 + 1] = ty * inv;
    }
}

__global__ __launch_bounds__(256) void fc_logsoftmax_kernel(
    const float* __restrict__ bu, const float* __restrict__ td,
    const float* __restrict__ Wf, const float* __restrict__ bf,
    float* __restrict__ out, int g)
{
    const int wid  = (int)((blockIdx.x * 256u + threadIdx.x) >> 6);
    const int lane = threadIdx.x & 63;
    if (wid >= g) return;
    const float f0 = bu[(size_t)wid * FD + lane];
    const float f1 = bu[(size_t)wid * FD + 64 + lane];
    const float f2 = td[(size_t)wid * FD + lane];
    const float f3 = td[(size_t)wid * FD + 64 + lane];
    const float4 w0 = *(const float4*)&Wf[lane * 4];
    const float4 w1 = *(const float4*)&Wf[(64 + lane) * 4];
    const float4 w2 = *(const float4*)&Wf[(128 + lane) * 4];
    const float4 w3 = *(const float4*)&Wf[(192 + lane) * 4];
    float l0 = f0 * w0.x + f1 * w1.x + f2 * w2.x + f3 * w3.x;
    float l1 = f0 * w0.y + f1 * w1.y + f2 * w2.y + f3 * w3.y;
    float l2 = f0 * w0.z + f1 * w1.z + f2 * w2.z + f3 * w3.z;
    float l3 = f0 * w0.w + f1 * w1.w + f2 * w2.w + f3 * w3.w;
    #pragma unroll
    for (int off = 32; off; off >>= 1) {
        l0 += __shfl_xor(l0, off, 64);
        l1 += __shfl_xor(l1, off, 64);
        l2 += __shfl_xor(l2, off, 64);
        l3 += __shfl_xor(l3, off, 64);
    }
    if (lane == 0) {
        l0 += bf[0]; l1 += bf[1]; l2 += bf[2]; l3 += bf[3];
        float m = fmaxf(fmaxf(l0, l1), fmaxf(l2, l3));
        float ssum = expf(l0 - m) + expf(l1 - m) + expf(l2 - m) + expf(l3 - m);
        float ls = logf(ssum);
        out[(size_t)wid * 4 + 0] = l0 - m - ls;
        out[(size_t)wid * 4 + 1] = l1 - m - ls;
        out[(size_t)wid * 4 + 2] = l2 - m - ls;
        out[(size_t)wid * 4 + 3] = l3 - m - ls;
    }
}

extern "C" void kernel_launch(void* const* d_in, const int* in_sizes, int n_in,
                              void* d_out, int out_size, void* d_ws, size_t ws_size,
                              hipStream_t stream)
{
    const float* x      = (const float*)d_in[0];
    const int*   td_ei  = (const int*)d_in[1];
    const int*   bu_ei  = (const int*)d_in[2];
    const int*   batch  = (const int*)d_in[3];
    const float* td_W1  = (const float*)d_in[4];
    const float* td_as1 = (const float*)d_in[5];
    const float* td_ad1 = (const float*)d_in[6];
    const float* td_b1  = (const float*)d_in[7];
    const float* td_W2  = (const float*)d_in[8];
    const float* td_as2 = (const float*)d_in[9];
    const float* td_ad2 = (const float*)d_in[10];
    const float* td_b2  = (const float*)d_in[11];
    const float* bu_W1  = (const float*)d_in[12];
    const float* bu_as1 = (const float*)d_in[13];
    const float* bu_ad1 = (const float*)d_in[14];
    const float* bu_b1  = (const float*)d_in[15];
    const float* bu_W2  = (const float*)d_in[16];
    const float* bu_as2 = (const float*)d_in[17];
    const float* bu_ad2 = (const float*)d_in[18];
    const float* bu_b2  = (const float*)d_in[19];
    const float* fc_W   = (const float*)d_in[20];
    const float* fc_b   = (const float*)d_in[21];

    const int N  = in_sizes[0] / FD;
    const int E  = in_sizes[1] / 2;
    const int G  = out_size / 4;
    const int N2 = 2 * N;
    const int NB   = (N + 255) / 256;          // coarse buckets per branch (391)
    const int NBLK = (E + CHK - 1) / CHK;      // count blocks per branch (196)
    const int TN   = 2 * NB * NBLK;            // table entries (153K)
    const int tnb  = (TN + SB - 1) / SB;       // scan blocks (300, <=512)
    const int gx   = (N + 63) / 64;

    char* p = (char*)d_ws;
    unsigned short* h16 = (unsigned short*)p; p += roundup256((size_t)N2 * FD * 2);
    unsigned short* o16 = (unsigned short*)p; p += roundup256((size_t)N2 * FD * 2);
    int* esorted  = (int*)p; p += roundup256((size_t)2 * E * 4);
    int* bucketed = (int*)p; p += roundup256((size_t)2 * E * 4);
    int* table    = (int*)p; p += roundup256((size_t)(TN + 1) * 4);
    float* als  = (float*)p;  p += roundup256((size_t)N2 * 4);
    float* ald  = (float*)p;  p += roundup256((size_t)N2 * 4);
    int* rowptr = (int*)p;    p += roundup256((size_t)(N2 + 1) * 4);
    int* bsum   = (int*)p;    p += roundup256((size_t)SB * 4);
    unsigned short* wfrag = (unsigned short*)p; p += roundup256((size_t)4 * 16384 * 2);
    float* pooled_td = (float*)p; p += roundup256((size_t)G * FD * 4);
    float* pooled_bu = (float*)p; p += roundup256((size_t)G * FD * 4);

    const dim3 blk256(256);
    const dim3 gGemm(gx, 2);
    const dim3 gAgg(((unsigned)N2 * 32 + 255) / 256);

    // W fragment prep
    wprep_kernel<<<dim3(256), blk256, 0, stream>>>(td_W1, bu_W1, td_W2, bu_W2, wfrag);

    // atomic-free CSR build (both branches)
    bucket_count_kernel<<<dim3(2 * NBLK), blk256, 0, stream>>>(td_ei, bu_ei, table, E, NB, NBLK);
    scan_block_kernel<<<dim3(tnb), dim3(SB), 0, stream>>>(table, table, bsum, TN);
    scan_top_kernel<<<dim3(1), dim3(SB), 0, stream>>>(bsum, tnb);
    scan_add_kernel<<<dim3(tnb), dim3(SB), 0, stream>>>(table, bsum, TN, 2 * E);
    bucket_scatter_kernel<<<dim3(2 * NBLK), blk256, 0, stream>>>(td_ei, bu_ei, table, bucketed, E, NB, NBLK);
    bucket_finalize_kernel<<<dim3(2 * NB), blk256, 0, stream>>>(table, bucketed, esorted, rowptr, E, N, NB, NBLK);

    // layer 1: x(f32, shared) -> h16(2N) -> o16(2N)
    gemm_mfma_kernel<true><<<gGemm, blk256, 0, stream>>>(
        x, (const unsigned short*)nullptr, wfrag,
        td_as1, td_ad1, bu_as1, bu_ad1, h16, als, ald, N, 0);
    gat_aggregate_kernel<<<gAgg, blk256, 0, stream>>>(
        rowptr, esorted, als, ald, h16, td_b1, bu_b1, o16, N2, N);

    // layer 2: o16 -> h16 -> o16
    gemm_mfma_kernel<false><<<gGemm, blk256, 0, stream>>>(
        (const float*)nullptr, o16, wfrag + 2 * 16384,
        td_as2, td_ad2, bu_as2, bu_ad2, h16, als, ald, N, N);
    gat_aggregate_kernel<<<gAgg, blk256, 0, stream>>>(
        rowptr, esorted, als, ald, h16, td_b2, bu_b2, o16, N2, N);

    // pool + fc
    pool_mean_kernel<<<dim3(G, 2), blk256, 0, stream>>>(o16, batch, pooled_td, pooled_bu, N);
    fc_logsoftmax_kernel<<<dim3((G + 3) / 4), blk256, 0, stream>>>(
        pooled_bu, pooled_td, fc_W, fc_b, (float*)d_out, G);
}